// Round 5
// baseline (1073.265 us; speedup 1.0000x reference)
//
#include <hip/hip_runtime.h>
#include <hip/hip_bf16.h>
#include <cstdint>
#include <cstddef>

// Problem dims (fixed)
#define SEQ 4096
#define DM  512
#define NH  8
#define DPH 64
#define FF  2048

using short8 = __attribute__((ext_vector_type(8))) short;
using f32x4  = __attribute__((ext_vector_type(4))) float;

__device__ inline float b2f(unsigned short u) {
    union { unsigned int i; float f; } c; c.i = ((unsigned int)u) << 16; return c.f;
}
__device__ inline unsigned short f2b(float f) {
    union { float f; unsigned int u; } c; c.f = f;
    unsigned int u = c.u;
    return (unsigned short)((u + 0x7fffu + ((u >> 16) & 1u)) >> 16);
}

// ---------------------------------------------------------------------------
// Tiled bf16 MFMA GEMM: C = A @ BT^T (+bias, +res, relu).
// Tile BM x BN, BK=32; 4 waves in 2x2; per-wave (BM/2)x(BN/2).
// LDS padded [row][40] bf16. Reg-staged, 2 barriers/K-step, next-K prefetch.
// QKV=1: N=1536 fused projection; epilogue routes col n>>9 to Cb/Ck/Cv
// (each [4096][512] bf16). K accumulation order k0-ascending -> bit-identical.
// grid = (N/BN, M/BM)
// ---------------------------------------------------------------------------
template<int BM, int BN, int QKV>
__global__ __launch_bounds__(256) void tgemm_kernel(
    const unsigned short* __restrict__ A, const unsigned short* __restrict__ BT,
    const float* __restrict__ bias, const unsigned short* __restrict__ res,
    unsigned short* __restrict__ Cb, float* __restrict__ Cf,
    unsigned short* __restrict__ Ck, unsigned short* __restrict__ Cv,
    int M, int N, int K, int relu)
{
    constexpr int MI  = BM / 32;          // m-frags per wave
    constexpr int NI  = BN / 32;          // n-frags per wave
    constexpr int CPT = (BM + BN) / 64;   // staging chunks per thread

    __shared__ __align__(16) unsigned short As[BM * 40];
    __shared__ __align__(16) unsigned short Bs[BN * 40];

    const int t    = threadIdx.x;
    const int lane = t & 63;
    const int wid  = t >> 6;
    const int wr   = wid >> 1, wc = wid & 1;
    const int quad = lane >> 4, cl = lane & 15;
    const int m0 = blockIdx.y * BM;
    const int n0 = blockIdx.x * BN;

    const unsigned short* gsrc[CPT];
    unsigned short*       ldst[CPT];
#pragma unroll
    for (int i = 0; i < CPT; ++i) {
        const int c = t + i * 256;
        const int row = c >> 2, kc = c & 3;
        if (row < BM) {
            gsrc[i] = A + (size_t)(m0 + row) * K + kc * 8;
            ldst[i] = As + row * 40 + kc * 8;
        } else {
            gsrc[i] = BT + (size_t)(n0 + row - BM) * K + kc * 8;
            ldst[i] = Bs + (row - BM) * 40 + kc * 8;
        }
    }

    f32x4 acc[MI][NI];
    const f32x4 zero4 = {0.f, 0.f, 0.f, 0.f};
#pragma unroll
    for (int mi = 0; mi < MI; ++mi)
#pragma unroll
        for (int ni = 0; ni < NI; ++ni) acc[mi][ni] = zero4;

    short8 pf[CPT];
#pragma unroll
    for (int i = 0; i < CPT; ++i) pf[i] = *(const short8*)(gsrc[i]);

    for (int k0 = 0; k0 < K; k0 += 32) {
        __syncthreads();   // previous step's LDS reads complete
#pragma unroll
        for (int i = 0; i < CPT; ++i) *(short8*)(ldst[i]) = pf[i];
        __syncthreads();   // tile visible

        const int kn = k0 + 32;
        if (kn < K) {      // prefetch next K-slice under the MFMAs
#pragma unroll
            for (int i = 0; i < CPT; ++i) pf[i] = *(const short8*)(gsrc[i] + kn);
        }

        short8 af[MI], bf[NI];
#pragma unroll
        for (int mi = 0; mi < MI; ++mi)
            af[mi] = *(const short8*)(&As[(wr * (BM / 2) + mi * 16 + cl) * 40 + quad * 8]);
#pragma unroll
        for (int ni = 0; ni < NI; ++ni)
            bf[ni] = *(const short8*)(&Bs[(wc * (BN / 2) + ni * 16 + cl) * 40 + quad * 8]);
#pragma unroll
        for (int mi = 0; mi < MI; ++mi)
#pragma unroll
            for (int ni = 0; ni < NI; ++ni)
                acc[mi][ni] = __builtin_amdgcn_mfma_f32_16x16x32_bf16(af[mi], bf[ni], acc[mi][ni], 0, 0, 0);
    }

#pragma unroll
    for (int ni = 0; ni < NI; ++ni) {
        const int n = n0 + wc * (BN / 2) + ni * 16 + cl;
        const float bv = bias ? bias[n] : 0.f;
#pragma unroll
        for (int mi = 0; mi < MI; ++mi) {
#pragma unroll
            for (int r = 0; r < 4; ++r) {
                const int row = m0 + wr * (BM / 2) + mi * 16 + quad * 4 + r;
                float v = acc[mi][ni][r] + bv;
                if (QKV) {
                    const int sec = n >> 9, nc = n & 511;
                    unsigned short* dst = sec == 0 ? Cb : (sec == 1 ? Ck : Cv);
                    dst[(size_t)row * 512 + nc] = f2b(v);
                } else {
                    const size_t idx = (size_t)row * N + n;
                    if (res)  v += b2f(res[idx]);
                    if (relu) v = fmaxf(v, 0.f);
                    if (Cf) Cf[idx] = v;
                    else    Cb[idx] = f2b(v);
                }
            }
        }
    }
}

// ---------------------------------------------------------------------------
// fp32 -> bf16 transpose (weights): dst[c][r] = (bf16)src[r][c]
// ---------------------------------------------------------------------------
__global__ __launch_bounds__(256) void transpose_cast_kernel(
    const float* __restrict__ src, unsigned short* __restrict__ dst, int R, int C)
{
    __shared__ float tile[32][33];
    const int c0 = blockIdx.x * 32, r0 = blockIdx.y * 32;
    const int tx = threadIdx.x & 31, ty = threadIdx.x >> 5;  // 32 x 8
#pragma unroll
    for (int i = 0; i < 4; ++i)
        tile[ty + i * 8][tx] = src[(size_t)(r0 + ty + i * 8) * C + c0 + tx];
    __syncthreads();
#pragma unroll
    for (int i = 0; i < 4; ++i)
        dst[(size_t)(c0 + ty + i * 8) * R + r0 + tx] = f2b(tile[tx][ty + i * 8]);
}

// ---------------------------------------------------------------------------
// bf16 transpose (per-head V): dst[c][r] = src[r][c]; grid=(C/32, R/32, batch)
// ---------------------------------------------------------------------------
__global__ __launch_bounds__(256) void transpose_kernel(
    const unsigned short* __restrict__ src, unsigned short* __restrict__ dst,
    int R, int C)
{
    __shared__ unsigned short tile[32][33];
    const long off = (long)blockIdx.z * (long)R * (long)C;
    src += off; dst += off;
    const int c0 = blockIdx.x * 32, r0 = blockIdx.y * 32;
    const int tx = threadIdx.x & 31, ty = threadIdx.x >> 5;
#pragma unroll
    for (int i = 0; i < 4; ++i)
        tile[ty + i * 8][tx] = src[(size_t)(r0 + ty + i * 8) * C + c0 + tx];
    __syncthreads();
#pragma unroll
    for (int i = 0; i < 4; ++i)
        dst[(size_t)(c0 + ty + i * 8) * R + r0 + tx] = tile[tx][ty + i * 8];
}

// ---------------------------------------------------------------------------
// fp32 -> bf16 elementwise cast (x). n4 = elements/4.
// ---------------------------------------------------------------------------
__global__ __launch_bounds__(256) void cast_kernel(
    const float* __restrict__ src, unsigned short* __restrict__ dst, int n4)
{
    const int i = blockIdx.x * 256 + threadIdx.x;
    if (i >= n4) return;
    const float4 v = ((const float4*)src)[i];
    union { unsigned short s[4]; unsigned long long u; } p;
    p.s[0] = f2b(v.x); p.s[1] = f2b(v.y); p.s[2] = f2b(v.z); p.s[3] = f2b(v.w);
    ((unsigned long long*)dst)[i] = p.u;
}

// ---------------------------------------------------------------------------
// bias concat for fused QKV: bqkv[0:512)=bq, [512:1024)=bk, [1024:1536)=bv
// ---------------------------------------------------------------------------
__global__ __launch_bounds__(256) void bias_concat_kernel(
    const float* __restrict__ bq, const float* __restrict__ bk,
    const float* __restrict__ bv, float* __restrict__ bqkv)
{
    const int i = blockIdx.x * 256 + threadIdx.x;
    if (i >= 1536) return;
    bqkv[i] = i < 512 ? bq[i] : (i < 1024 ? bk[i - 512] : bv[i - 1024]);
}

// ---------------------------------------------------------------------------
// Fused attention ctx kernel: online softmax stats + P@V, NO att stores.
// R4 post-mortem: per-iteration att stores serialized the loop via the shared
// per-wave vmcnt FIFO (load-use waits retire only after older stores ack);
// 1.43 TB/s invariant across occupancy/granularity changes. Fix: this kernel
// has no global stores in the loop; att written by att_write_kernel (below)
// using the (m, inv) stats this kernel writes (tiny, 64 KB).
// Block = 4 waves; 16 q-rows; wave w owns cols [w*1024, +1024). grid=2048.
// ---------------------------------------------------------------------------
__global__ __launch_bounds__(256, 8) void fused_attn_kernel(
    const unsigned short* __restrict__ qb,   // [8][4096][64] bf16 (direct view)
    const unsigned short* __restrict__ kb,   // [8][4096][64] bf16
    const unsigned short* __restrict__ vT,   // [8][64][4096] bf16
    unsigned short* __restrict__ ctx,        // [8][4096][64] bf16
    float* __restrict__ m_ws,                // [8][4096] row max
    float* __restrict__ inv_ws)              // [8][4096] 1/rowsum
{
    __shared__ __align__(16) float Pl[4][16 * 36];   // per-wave P transpose buf
    __shared__ float smM[4][16];
    __shared__ float smS[4][16];
    __shared__ __align__(16) float cbuf[2][16 * 68]; // ctx combine buffers

    const int id    = blockIdx.x;
    const int h     = id & 7;
    const int strip = id >> 3;               // 0..255
    const int lane  = threadIdx.x & 63;
    const int w     = threadIdx.x >> 6;      // col-quarter 0..3
    const int quad  = lane >> 4, col = lane & 15;
    const int m0    = strip * 16;

    const unsigned short* Qh = qb + (size_t)h * SEQ * DPH;
    const unsigned short* Kh = kb + (size_t)h * SEQ * DPH;
    const unsigned short* Vh = vT + (size_t)h * SEQ * DPH;
    unsigned short* ctxh = ctx + (size_t)h * SEQ * DPH;

    const unsigned short* qrow = Qh + (size_t)(m0 + col) * DPH + quad * 8;
    const short8 aq0 = *(const short8*)(qrow);
    const short8 aq1 = *(const short8*)(qrow + 32);

    const unsigned short* kbase = Kh + (size_t)(w * 1024 + col) * DPH + quad * 8;
    const float SC = 0.125f;
    const f32x4 zero4 = {0.f, 0.f, 0.f, 0.f};

    float m[4], s[4];
#pragma unroll
    for (int r = 0; r < 4; ++r) { m[r] = -1e30f; s[r] = 0.f; }

    // ---- Phase 1: online max/sum over this wave's 1024 columns -------------
#pragma unroll 2
    for (int nt = 0; nt < 64; ++nt) {
        const unsigned short* kr = kbase + (size_t)nt * 16 * DPH;
        const short8 b0 = *(const short8*)(kr);
        const short8 b1 = *(const short8*)(kr + 32);
        f32x4 acc = zero4;
        acc = __builtin_amdgcn_mfma_f32_16x16x32_bf16(aq0, b0, acc, 0, 0, 0);
        acc = __builtin_amdgcn_mfma_f32_16x16x32_bf16(aq1, b1, acc, 0, 0, 0);
#pragma unroll
        for (int r = 0; r < 4; ++r) {
            const float v  = acc[r] * SC;
            const float nm = fmaxf(m[r], v);
            const float e  = __expf(fminf(m[r], v) - nm);   // the one real exp
            s[r] = (v > m[r]) ? fmaf(s[r], e, 1.f) : (s[r] + e);
            m[r] = nm;
        }
    }
#pragma unroll
    for (int off = 1; off < 16; off <<= 1) {
#pragma unroll
        for (int r = 0; r < 4; ++r) {
            const float mo = __shfl_xor(m[r], off);
            const float so = __shfl_xor(s[r], off);
            const float nm = fmaxf(m[r], mo);
            s[r] = s[r] * __expf(m[r] - nm) + so * __expf(mo - nm);
            m[r] = nm;
        }
    }
    if (col == 0) {
#pragma unroll
        for (int r = 0; r < 4; ++r) { smM[w][quad * 4 + r] = m[r]; smS[w][quad * 4 + r] = s[r]; }
    }
    __syncthreads();
    // 4-way combine in fixed order -> identical (m, inv) on every wave
    float inv[4];
#pragma unroll
    for (int r = 0; r < 4; ++r) {
        const int row = quad * 4 + r;
        float M = smM[0][row], S = smS[0][row];
#pragma unroll
        for (int ww = 1; ww < 4; ++ww) {
            const float mo = smM[ww][row];
            const float so = smS[ww][row];
            const float nm = fmaxf(M, mo);
            S = S * __expf(M - nm) + so * __expf(mo - nm);
            M = nm;
        }
        m[r] = M;
        inv[r] = 1.f / S;
    }
    if (w == 0 && col == 0) {
#pragma unroll
        for (int r = 0; r < 4; ++r) {
            m_ws[(size_t)h * SEQ + m0 + quad * 4 + r]   = m[r];
            inv_ws[(size_t)h * SEQ + m0 + quad * 4 + r] = inv[r];
        }
    }

    // ---- Phase 2: recompute, normalize, accumulate P@V (no global stores) --
    f32x4 cacc[4];
#pragma unroll
    for (int t = 0; t < 4; ++t) cacc[t] = zero4;

    float* Pw = Pl[w];
    for (int pr = 0; pr < 32; ++pr) {
#pragma unroll
        for (int sub = 0; sub < 2; ++sub) {
            const int ntl = pr * 2 + sub;
            const unsigned short* kr = kbase + (size_t)ntl * 16 * DPH;
            const short8 b0 = *(const short8*)(kr);
            const short8 b1 = *(const short8*)(kr + 32);
            f32x4 acc = zero4;
            acc = __builtin_amdgcn_mfma_f32_16x16x32_bf16(aq0, b0, acc, 0, 0, 0);
            acc = __builtin_amdgcn_mfma_f32_16x16x32_bf16(aq1, b1, acc, 0, 0, 0);
#pragma unroll
            for (int r = 0; r < 4; ++r) {
                const float p = __expf(fmaf(acc[r], SC, -m[r])) * inv[r];
                Pw[(quad * 4 + r) * 36 + sub * 16 + col] = p;    // LDS transpose
            }
        }
        // A-fragment: lane(col,quad) reads P[col][quad*8 .. +7] (fp32 -> bf16)
        const float4 pa0 = *(const float4*)(Pw + col * 36 + quad * 8);
        const float4 pa1 = *(const float4*)(Pw + col * 36 + quad * 8 + 4);
        union { unsigned short us[8]; short8 v; } ap;
        ap.us[0] = f2b(pa0.x); ap.us[1] = f2b(pa0.y);
        ap.us[2] = f2b(pa0.z); ap.us[3] = f2b(pa0.w);
        ap.us[4] = f2b(pa1.x); ap.us[5] = f2b(pa1.y);
        ap.us[6] = f2b(pa1.z); ap.us[7] = f2b(pa1.w);

        const int kg = w * 1024 + pr * 32;
        const unsigned short* vb0 = Vh + (size_t)col * SEQ + kg + quad * 8;
#pragma unroll
        for (int t = 0; t < 4; ++t) {
            const short8 bv = *(const short8*)(vb0 + (size_t)t * 16 * SEQ);
            cacc[t] = __builtin_amdgcn_mfma_f32_16x16x32_bf16(ap.v, bv, cacc[t], 0, 0, 0);
        }
    }

    // ---- combine ctx across 4 col-quarter waves (2 LDS rounds) -------------
    if (w & 1) {
        float* cb = cbuf[w >> 1];
#pragma unroll
        for (int t = 0; t < 4; ++t)
#pragma unroll
            for (int r = 0; r < 4; ++r)
                cb[(quad * 4 + r) * 68 + t * 16 + col] = cacc[t][r];
    }
    __syncthreads();
    if (!(w & 1)) {
        const float* cb = cbuf[w >> 1];
#pragma unroll
        for (int t = 0; t < 4; ++t)
#pragma unroll
            for (int r = 0; r < 4; ++r)
                cacc[t][r] += cb[(quad * 4 + r) * 68 + t * 16 + col];
    }
    __syncthreads();
    if (w == 2) {
#pragma unroll
        for (int t = 0; t < 4; ++t)
#pragma unroll
            for (int r = 0; r < 4; ++r)
                cbuf[0][(quad * 4 + r) * 68 + t * 16 + col] = cacc[t][r];
    }
    __syncthreads();
    if (w == 0) {
#pragma unroll
        for (int t = 0; t < 4; ++t) {
#pragma unroll
            for (int r = 0; r < 4; ++r) {
                const float v = cacc[t][r] + cbuf[0][(quad * 4 + r) * 68 + t * 16 + col];
                ctxh[(size_t)(m0 + quad * 4 + r) * DPH + t * 16 + col] = f2b(v);
            }
        }
    }
}

// ---------------------------------------------------------------------------
// att writer: recompute scores per 64x256 tile, p = exp(s*SC - m)*inv with
// (m, inv) from workspace, compute-ALL-then-store-ALL per wave (terminal
// store burst; no load-use after stores in-wave -> no vmcnt serialization).
// Full-128B-line stores via per-wave LDS transpose (v3 pattern).
// Block = 4 waves; wave w = rows [rb*64 + w*16, +16), cols [ct*256, +256).
// grid = 8192 (h = id&7 for XCD L2 affinity of K).
// Bit-identical p to fused kernel (same MFMA order, same formula).
// ---------------------------------------------------------------------------
__global__ __launch_bounds__(256) void att_write_kernel(
    const unsigned short* __restrict__ qb,
    const unsigned short* __restrict__ kb,
    const float* __restrict__ m_ws, const float* __restrict__ inv_ws,
    float* __restrict__ att)
{
    __shared__ __align__(16) float Pl[4][16 * 36];

    const int id   = blockIdx.x;
    const int h    = id & 7;
    const int rt   = id >> 3;      // 0..1023
    const int ct   = rt & 15;      // col tile 0..15
    const int rb   = rt >> 4;      // row block 0..63
    const int lane = threadIdx.x & 63;
    const int w    = threadIdx.x >> 6;
    const int quad = lane >> 4, col = lane & 15;
    const int m0   = rb * 64 + w * 16;
    const int c0   = ct * 256;

    const unsigned short* Qh = qb + (size_t)h * SEQ * DPH;
    const unsigned short* Kh = kb + (size_t)h * SEQ * DPH;
    float* atth = att + (size_t)h * SEQ * SEQ;

    const unsigned short* qrow = Qh + (size_t)(m0 + col) * DPH + quad * 8;
    const short8 aq0 = *(const short8*)(qrow);
    const short8 aq1 = *(const short8*)(qrow + 32);

    float mrow[4], invr[4];
#pragma unroll
    for (int r = 0; r < 4; ++r) {
        mrow[r] = m_ws[(size_t)h * SEQ + m0 + quad * 4 + r];
        invr[r] = inv_ws[(size_t)h * SEQ + m0 + quad * 4 + r];
    }

    const unsigned short* kbase = Kh + (size_t)(c0 + col) * DPH + quad * 8;
    const float SC = 0.125f;
    const f32x4 zero4 = {0.f, 0.f, 0.f, 0.f};

    // compute all 16 col-frags, exp applied, held in registers
    f32x4 p[16];
#pragma unroll
    for (int t = 0; t < 16; ++t) {
        const unsigned short* kr = kbase + (size_t)t * 16 * DPH;
        const short8 b0 = *(const short8*)(kr);
        const short8 b1 = *(const short8*)(kr + 32);
        f32x4 acc = zero4;
        acc = __builtin_amdgcn_mfma_f32_16x16x32_bf16(aq0, b0, acc, 0, 0, 0);
        acc = __builtin_amdgcn_mfma_f32_16x16x32_bf16(aq1, b1, acc, 0, 0, 0);
#pragma unroll
        for (int r = 0; r < 4; ++r)
            p[t][r] = __expf(fmaf(acc[r], SC, -mrow[r])) * invr[r];
    }

    // terminal store burst: per 32-col group, LDS transpose -> 128B-line stores
    float* Pw = Pl[w];
    const int srow2  = lane >> 3;   // 0..7
    const int schunk = lane & 7;    // 0..7
    float* abase = atth + (size_t)m0 * SEQ + c0;
#pragma unroll
    for (int g = 0; g < 8; ++g) {
#pragma unroll
        for (int half = 0; half < 2; ++half) {
            const int t = g * 2 + half;
#pragma unroll
            for (int r = 0; r < 4; ++r)
                Pw[(quad * 4 + r) * 36 + half * 16 + col] = p[t][r];
        }
#pragma unroll
        for (int sset = 0; sset < 2; ++sset) {
            const int prow = srow2 + sset * 8;
            const float4 pv = *(const float4*)(Pw + prow * 36 + schunk * 4);
            *(float4*)(abase + (size_t)prow * SEQ + g * 32 + schunk * 4) = pv;
        }
    }
}

// ---------------------------------------------------------------------------
// LayerNorm over rows of 512 fp32 -> fp32 out. One block (256 thr) per row.
// ---------------------------------------------------------------------------
__global__ __launch_bounds__(256) void ln_kernel(
    const float* __restrict__ pre,
    const float* __restrict__ gamma, const float* __restrict__ beta,
    float* __restrict__ out)
{
    __shared__ float redS[4], redQ[4];
    const float* p = pre + (size_t)blockIdx.x * 512;
    const int t = threadIdx.x;
    const int w = t >> 6, lane = t & 63;

    const float2 xv = *(const float2*)(p + t * 2);
    float s = xv.x + xv.y;
    float q = xv.x * xv.x + xv.y * xv.y;
#pragma unroll
    for (int off = 32; off; off >>= 1) {
        s += __shfl_xor(s, off);
        q += __shfl_xor(q, off);
    }
    if (lane == 0) { redS[w] = s; redQ[w] = q; }
    __syncthreads();
    s = redS[0] + redS[1] + redS[2] + redS[3];
    q = redQ[0] + redQ[1] + redQ[2] + redQ[3];

    const float mu  = s * (1.f / 512.f);
    const float var = q * (1.f / 512.f) - mu * mu;
    const float rs  = rsqrtf(var + 1e-5f);

    const size_t o = (size_t)blockIdx.x * 512 + t * 2;
    out[o]     = (xv.x - mu) * rs * gamma[t * 2]     + beta[t * 2];
    out[o + 1] = (xv.y - mu) * rs * gamma[t * 2 + 1] + beta[t * 2 + 1];
}

// ---------------------------------------------------------------------------
extern "C" void kernel_launch(void* const* d_in, const int* in_sizes, int n_in,
                              void* d_out, int out_size, void* d_ws, size_t ws_size,
                              hipStream_t stream)
{
    (void)in_sizes; (void)n_in; (void)out_size; (void)ws_size;

    const float* x     = (const float*)d_in[0];
    const float* wq    = (const float*)d_in[1];
    const float* bq    = (const float*)d_in[2];
    const float* wk    = (const float*)d_in[3];
    const float* bk    = (const float*)d_in[4];
    const float* wv    = (const float*)d_in[5];
    const float* bv    = (const float*)d_in[6];
    const float* wo    = (const float*)d_in[7];
    const float* bo    = (const float*)d_in[8];
    const float* w1    = (const float*)d_in[9];
    const float* b1    = (const float*)d_in[10];
    const float* w2    = (const float*)d_in[11];
    const float* b2    = (const float*)d_in[12];
    const float* gamma = (const float*)d_in[13];
    const float* beta  = (const float*)d_in[14];

    float* out = (float*)d_out;
    float* att = out + (size_t)SEQ * DM;  // attn region: 8*4096*4096 fp32

    char* wsp = (char*)d_ws;
    auto alloc = [&](size_t bytes) {
        char* p = wsp;
        wsp += (bytes + 255) & ~(size_t)255;
        return p;
    };
    unsigned short* wqkvT = (unsigned short*)alloc((size_t)3 * DM * DM * 2); // [1536][512]
    unsigned short* woT   = (unsigned short*)alloc((size_t)DM * DM * 2);
    unsigned short* w1T   = (unsigned short*)alloc((size_t)DM * FF * 2);
    unsigned short* w2T   = (unsigned short*)alloc((size_t)FF * DM * 2);
    unsigned short* xb    = (unsigned short*)alloc((size_t)SEQ * DM * 2);
    unsigned short* qb    = (unsigned short*)alloc((size_t)SEQ * DM * 2);
    unsigned short* kb    = (unsigned short*)alloc((size_t)SEQ * DM * 2);
    unsigned short* vb    = (unsigned short*)alloc((size_t)SEQ * DM * 2);
    unsigned short* vT    = (unsigned short*)alloc((size_t)SEQ * DM * 2);
    unsigned short* ctx   = (unsigned short*)alloc((size_t)SEQ * DM * 2);
    unsigned short* aout  = (unsigned short*)alloc((size_t)SEQ * DM * 2);
    unsigned short* ffn1  = (unsigned short*)alloc((size_t)SEQ * FF * 2);
    float*          pre   = (float*)alloc((size_t)SEQ * DM * 4);
    float*          bqkv  = (float*)alloc((size_t)3 * DM * 4);
    float*          m_ws  = (float*)alloc((size_t)NH * SEQ * 4);
    float*          i_ws  = (float*)alloc((size_t)NH * SEQ * 4);

    const dim3 blk(256);

    // x -> bf16
    cast_kernel<<<dim3((SEQ * DM / 4 + 255) / 256), blk, 0, stream>>>(x, xb, SEQ * DM / 4);

    // Weight transposes+casts -> [out,in] row-major bf16 (BT form)
    transpose_cast_kernel<<<dim3(16, 16), blk, 0, stream>>>(wq, wqkvT, DM, DM);
    transpose_cast_kernel<<<dim3(16, 16), blk, 0, stream>>>(wk, wqkvT + (size_t)DM * DM, DM, DM);
    transpose_cast_kernel<<<dim3(16, 16), blk, 0, stream>>>(wv, wqkvT + (size_t)2 * DM * DM, DM, DM);
    transpose_cast_kernel<<<dim3(16, 16), blk, 0, stream>>>(wo, woT, DM, DM);
    transpose_cast_kernel<<<dim3(64, 16), blk, 0, stream>>>(w1, w1T, DM, FF);
    transpose_cast_kernel<<<dim3(16, 64), blk, 0, stream>>>(w2, w2T, FF, DM);
    bias_concat_kernel<<<dim3(6), blk, 0, stream>>>(bq, bk, bv, bqkv);

    // Fused QKV projection: [4096,1536] = x @ [wq|wk|wv] + b, routed to q/k/v
    tgemm_kernel<64, 64, 1><<<dim3(24, 64), blk, 0, stream>>>(
        xb, wqkvT, bqkv, nullptr, qb, nullptr, kb, vb, SEQ, 3 * DM, DM, 0);

    // Per-head V transpose: [4096,64] -> [64,4096], batch=8
    transpose_kernel<<<dim3(2, 128, 8), blk, 0, stream>>>(vb, vT, SEQ, DPH);

    // Fused ctx: softmax stats + P@V (no att stores); writes m/inv
    fused_attn_kernel<<<dim3(2048), blk, 0, stream>>>(qb, kb, vT, ctx, m_ws, i_ws);

    // att writer: recompute scores, normalize, stream att (terminal bursts)
    att_write_kernel<<<dim3(8192), blk, 0, stream>>>(qb, kb, m_ws, i_ws, att);

    // attn_out = ctx @ wo + bo + x
    tgemm_kernel<64, 64, 0><<<dim3(8, 64), blk, 0, stream>>>(
        ctx, woT, bo, xb, aout, nullptr, nullptr, nullptr, SEQ, DM, DM, 0);

    // ffn1 = relu(attn_out @ w1 + b1)
    tgemm_kernel<128, 128, 0><<<dim3(16, 32), blk, 0, stream>>>(
        aout, w1T, b1, nullptr, ffn1, nullptr, nullptr, nullptr, SEQ, FF, DM, 1);

    // pre-LN = ffn1 @ w2 + b2 + attn_out (fp32)
    tgemm_kernel<64, 64, 0><<<dim3(8, 64), blk, 0, stream>>>(
        ffn1, w2T, b2, aout, nullptr, pre, nullptr, nullptr, SEQ, DM, FF, 0);

    // LayerNorm -> out (fp32)
    ln_kernel<<<dim3(SEQ), blk, 0, stream>>>(pre, gamma, beta, out);
}